// Round 1
// baseline (402.881 us; speedup 1.0000x reference)
//
#include <hip/hip_runtime.h>
#include <math.h>

#define HW   56
#define DIMC 256
#define HID  1024

typedef __attribute__((ext_vector_type(8))) short bf16x8;
typedef __attribute__((ext_vector_type(4))) float f32x4;

__device__ __forceinline__ short f2bf(float f) {
  union { float fv; unsigned u; } v; v.fv = f;
  unsigned r = v.u + 0x7fffu + ((v.u >> 16) & 1u);
  return (short)(r >> 16);
}
__device__ __forceinline__ float bf2f(short s) {
  union { unsigned u; float fv; } v; v.u = ((unsigned)(unsigned short)s) << 16;
  return v.fv;
}
// gelu via sigmoid: v*sigmoid(1.702v); error reaches out scaled by gamma=1e-6.
__device__ __forceinline__ float gelu_fast(float v) {
  return v / (1.f + exp2f(-2.4556260f * v));
}

// ---------------------------------------------------------------------------
// prep_pack: weights -> bf16 MFMA-fragment-major (frag = 64 lanes x 16B = 1KB).
//  w1p frag (ch*2+nh)*8+k8 : n=ch*32+nh*16+l15, k=k8*32+q*8+j, elem w1[k][n]
//  w2p frag ch*16+nt2      : k=ch*32+q*8+j, c=nt2*16+l15,      elem w2[k][c]
// ---------------------------------------------------------------------------
__global__ void prep_pack(const float* __restrict__ w1, const float* __restrict__ w2,
                          short* __restrict__ w1p, short* __restrict__ w2p) {
  int g = blockIdx.x * 256 + threadIdx.x;
  int f = g >> 6, lane = g & 63;
  int l15 = lane & 15, q = lane >> 4;
  bf16x8 v;
  if (f < 512) {
    int k8 = f & 7, t = f >> 3, nt = t & 1, ch = t >> 1;
    int n = ch * 32 + nt * 16 + l15;
    int k = k8 * 32 + q * 8;
    #pragma unroll
    for (int j = 0; j < 8; ++j) v[j] = f2bf(w1[(k + j) * HID + n]);
    *(bf16x8*)(w1p + f * 512 + lane * 8) = v;
  } else {
    int f2 = f - 512;
    int nt2 = f2 & 15, ch = f2 >> 4;
    int k = ch * 32 + q * 8;
    int c = nt2 * 16 + l15;
    #pragma unroll
    for (int j = 0; j < 8; ++j) v[j] = f2bf(w2[(k + j) * DIMC + c]);
    *(bf16x8*)(w2p + f2 * 512 + lane * 8) = v;
  }
}

// ---------------------------------------------------------------------------
// conv_k: depthwise 7x7 + bias, active tiles only. Patch staged as aligned
// 16-float windows [w0-4, w0+12): 4 f32x4 per (c,r) row, compile-time w-edge
// masking. LDS [c][r][20] -> 2-way banks on sliding reads (free).
// ---------------------------------------------------------------------------
__global__ __launch_bounds__(256, 3) void conv_k(
    const float* __restrict__ x, const int* __restrict__ mask,
    const float* __restrict__ dw_w, const float* __restrict__ dw_b,
    short* __restrict__ ybuf) {
  __shared__ __align__(16) float s_patch[32 * 14 * 20];   // 35840 B
  __shared__ float s_wt[32 * 49];
  __shared__ __align__(16) short s_yout[32 * 64];

  int bid = blockIdx.x;
  int cgi = bid & 7; int t1 = bid >> 3;
  int wb = t1 % 7; int t2 = t1 / 7; int hb = t2 % 7; int b = t2 / 7;
  int tile = (b * 7 + hb) * 7 + wb;
  if (!mask[tile]) return;

  int tid = threadIdx.x;
  int h0 = hb * 8, w0 = wb * 8, cg0 = cgi * 32;

  for (int i = tid; i < 32 * 49; i += 256) s_wt[i] = dw_w[cg0 * 49 + i];

  // 32c x 14r x 4 vec-slots = 1792 slots, 7 per thread
  #pragma unroll
  for (int it = 0; it < 7; ++it) {
    int slot = tid + 256 * it;
    int j = slot & 3, row = slot >> 2;        // row = c*14 + r
    int c = row / 14, r = row - c * 14;
    int gh = h0 - 3 + r;
    f32x4 v = (f32x4){0.f, 0.f, 0.f, 0.f};
    bool ok = (gh >= 0) && (gh < HW) && !(wb == 0 && j == 0) && !(wb == 6 && j == 3);
    if (ok)
      v = *(const f32x4*)(x + ((long)(b * DIMC + cg0 + c) * HW + gh) * HW + (w0 - 4) + 4 * j);
    *(f32x4*)(s_patch + c * 280 + r * 20 + 4 * j) = v;
  }
  __syncthreads();

  int cl = tid >> 3, wq = tid & 7;
  float wt[49];
  #pragma unroll
  for (int j = 0; j < 49; ++j) wt[j] = s_wt[cl * 49 + j];
  float y[8] = {0.f, 0.f, 0.f, 0.f, 0.f, 0.f, 0.f, 0.f};
  #pragma unroll
  for (int r = 0; r < 14; ++r) {
    float row[7];
    #pragma unroll
    for (int j = 0; j < 7; ++j) row[j] = s_patch[cl * 280 + r * 20 + wq + 1 + j];
    #pragma unroll
    for (int dy = 0; dy < 7; ++dy) {
      int hh = r - dy;
      if (hh >= 0 && hh < 8) {
        #pragma unroll
        for (int dx = 0; dx < 7; ++dx) y[hh] += row[dx] * wt[dy * 7 + dx];
      }
    }
  }
  float db = dw_b[cg0 + cl];
  #pragma unroll
  for (int hh = 0; hh < 8; ++hh)
    s_yout[cl * 64 + hh * 8 + wq] = f2bf(y[hh] + db);
  __syncthreads();

  int c = tid >> 3, pd = (tid & 7) * 8;
  bf16x8 v = *(const bf16x8*)(s_yout + c * 64 + pd);
  *(bf16x8*)(ybuf + ((long)tile * DIMC + cg0 + c) * 64 + pd) = v;
}

// ---------------------------------------------------------------------------
// mlp_k v3: A (LN'd y) hoisted from LDS into REGISTERS before the chunk loop.
// The GEMM1 A-operand (32 rows x 256 c per wave = 16 bf16x8 frags = 64 VGPRs)
// is loop-invariant; v2 re-read it from LDS every chunk (16 ds_read_b128 x 32
// chunks = 512 redundant LDS reads/wave). v3 reads it once. Per-chunk LDS
// traffic drops from ~340 to ~110 cyc/wave -> LDS pipe no longer saturated.
// VGPR peak ~230 (z 64 + A 64 + w1r/w1n 64 + w2r 16 + temps) -> still 2 w/SIMD.
// LDS: s_a/s_del region 36864 | h 10240 | stats 4608 = 51712 -> 3 blocks/CU.
// ---------------------------------------------------------------------------
__global__ __launch_bounds__(256, 2) void mlp_k(
    const int* __restrict__ mask,
    const float* __restrict__ ln_w, const float* __restrict__ ln_b,
    const float* __restrict__ b1v, const float* __restrict__ b2v,
    const float* __restrict__ gammav,
    const short* __restrict__ w1p, const short* __restrict__ w2p,
    short* __restrict__ ybuf) {
  __shared__ __align__(16) char smem[51712];
  short* s_a   = (short*)smem;                  // [p 64][264] bf16 (LN'd A)
  short* s_del = (short*)smem;                  // alias: [c 256][72] bf16
  short* s_h   = (short*)(smem + 36864);        // 2 x [64 m][40]
  float* s_p1  = (float*)(smem + 47104);
  float* s_p2  = (float*)(smem + 48128);
  float* s_mu  = (float*)(smem + 49152);
  float* s_rs  = (float*)(smem + 49408);
  float* s_lnw = (float*)(smem + 49664);
  float* s_lnb = (float*)(smem + 50688);

  int tile = blockIdx.x;
  if (!mask[tile]) return;
  int tid = threadIdx.x;
  const short* ytile = ybuf + (long)tile * DIMC * 64;

  s_lnw[tid] = ln_w[tid];
  s_lnb[tid] = ln_b[tid];
  // load ybuf [c][p] -> transpose into s_a [p][c]; lane-per-channel so the
  // scalar u16 LDS writes spread across banks (c consecutive per lane).
  #pragma unroll
  for (int k = 0; k < 8; ++k) {
    int q4 = tid + 256 * k;
    int c = q4 & 255, pd = (q4 >> 8) * 8;
    bf16x8 v = *(const bf16x8*)(ytile + c * 64 + pd);
    #pragma unroll
    for (int j = 0; j < 8; ++j) s_a[(pd + j) * 264 + c] = v[j];
  }
  __syncthreads();

  {                                             // LN stats (pre-norm values)
    int p = tid & 63, cq = tid >> 6;
    float s1 = 0.f, s2 = 0.f;
    for (int c = cq * 64; c < cq * 64 + 64; ++c) {
      float v = bf2f(s_a[p * 264 + c]);
      s1 += v; s2 += v * v;
    }
    s_p1[cq * 64 + p] = s1; s_p2[cq * 64 + p] = s2;
  }
  __syncthreads();
  if (tid < 64) {
    float s1 = s_p1[tid] + s_p1[64 + tid] + s_p1[128 + tid] + s_p1[192 + tid];
    float s2 = s_p2[tid] + s_p2[64 + tid] + s_p2[128 + tid] + s_p2[192 + tid];
    float mu = s1 * (1.f / 256.f);
    float var = s2 * (1.f / 256.f) - mu * mu;
    s_mu[tid] = mu; s_rs[tid] = rsqrtf(var + 1e-6f);
  }
  __syncthreads();
  {                                             // normalize in place
    int p = tid & 63, cq = tid >> 6;
    float mu = s_mu[p], rs = s_rs[p];
    #pragma unroll
    for (int i = 0; i < 8; ++i) {
      int c0 = cq * 64 + i * 8;
      bf16x8 v = *(const bf16x8*)(s_a + p * 264 + c0);
      #pragma unroll
      for (int j = 0; j < 8; ++j)
        v[j] = f2bf((bf2f(v[j]) - mu) * rs * s_lnw[c0 + j] + s_lnb[c0 + j]);
      *(bf16x8*)(s_a + p * 264 + c0) = v;
    }
  }
  __syncthreads();

  const int wv = tid >> 6, lane = tid & 63;
  const int l15 = lane & 15, q = lane >> 4;
  const int mh = wv & 1, nh = wv >> 1;          // GEMM1: 2M x 2N wave split

  const short* aRow0 = s_a + (32 * mh + l15) * 264 + q * 8;
  const short* aRow1 = s_a + (32 * mh + 16 + l15) * 264 + q * 8;

  // hoist the loop-invariant GEMM1 A-operand into registers (64 VGPRs):
  // 16 ds_read_b128 ONCE instead of 16 per chunk (saves 512 reads/wave).
  bf16x8 a0f[8], a1f[8];
  #pragma unroll
  for (int k8 = 0; k8 < 8; ++k8) {
    a0f[k8] = *(const bf16x8*)(aRow0 + k8 * 32);
    a1f[k8] = *(const bf16x8*)(aRow1 + k8 * 32);
  }

  f32x4 z[4][4];                                // [jt][Mt], c = wv*64+jt*16+l15
  #pragma unroll
  for (int jt = 0; jt < 4; ++jt)
    #pragma unroll
    for (int Mt = 0; Mt < 4; ++Mt) z[jt][Mt] = (f32x4){0.f, 0.f, 0.f, 0.f};

  bf16x8 w1r[8];                                // prefetched W1 frags (ch=0)
  #pragma unroll
  for (int k8 = 0; k8 < 8; ++k8)
    w1r[k8] = *(const bf16x8*)(w1p + (long)(nh * 8 + k8) * 512 + lane * 8);

  for (int ch = 0; ch < 32; ++ch) {
    // issue W2 frags + bias now; consumed after barrier / after GEMM1
    bf16x8 w2r[4];
    #pragma unroll
    for (int jt = 0; jt < 4; ++jt)
      w2r[jt] = *(const bf16x8*)(w2p + (long)(ch * 16 + wv * 4 + jt) * 512 + lane * 8);
    float bb = b1v[ch * 32 + 16 * nh + l15];

    f32x4 acc0 = (f32x4){0.f, 0.f, 0.f, 0.f};
    f32x4 acc1 = (f32x4){0.f, 0.f, 0.f, 0.f};
    #pragma unroll
    for (int k8 = 0; k8 < 8; ++k8) {
      acc0 = __builtin_amdgcn_mfma_f32_16x16x32_bf16(a0f[k8], w1r[k8], acc0, 0, 0, 0);
      acc1 = __builtin_amdgcn_mfma_f32_16x16x32_bf16(a1f[k8], w1r[k8], acc1, 0, 0, 0);
    }
    bf16x8 w1n[8];                              // prefetch next chunk's W1
    if (ch < 31) {
      #pragma unroll
      for (int k8 = 0; k8 < 8; ++k8)
        w1n[k8] = *(const bf16x8*)(w1p + (long)(((ch + 1) * 2 + nh) * 8 + k8) * 512 + lane * 8);
    }
    short* hb = s_h + (ch & 1) * 2560;
    #pragma unroll
    for (int r = 0; r < 4; ++r) {
      hb[(32 * mh + 4 * q + r) * 40 + 16 * nh + l15]      = f2bf(gelu_fast(acc0[r] + bb));
      hb[(32 * mh + 16 + 4 * q + r) * 40 + 16 * nh + l15] = f2bf(gelu_fast(acc1[r] + bb));
    }
    __syncthreads();                            // h[ch&1] complete
    bf16x8 aH[4];
    #pragma unroll
    for (int Mt = 0; Mt < 4; ++Mt)
      aH[Mt] = *(const bf16x8*)(hb + (16 * Mt + l15) * 40 + q * 8);
    #pragma unroll
    for (int jt = 0; jt < 4; ++jt) {
      #pragma unroll
      for (int Mt = 0; Mt < 4; ++Mt)
        z[jt][Mt] = __builtin_amdgcn_mfma_f32_16x16x32_bf16(aH[Mt], w2r[jt], z[jt][Mt], 0, 0, 0);
    }
    if (ch < 31) {
      #pragma unroll
      for (int k8 = 0; k8 < 8; ++k8) w1r[k8] = w1n[k8];
    }
  }

  // epilogue: delta = (z+b2)*gamma -> s_del [c][72] -> ybuf in place
  #pragma unroll
  for (int jt = 0; jt < 4; ++jt) {
    int c = wv * 64 + jt * 16 + l15;
    float bb = b2v[c], gm = gammav[c];
    #pragma unroll
    for (int Mt = 0; Mt < 4; ++Mt) {
      #pragma unroll
      for (int r = 0; r < 4; ++r)
        s_del[c * 72 + 16 * Mt + 4 * q + r] = f2bf((z[jt][Mt][r] + bb) * gm);
    }
  }
  __syncthreads();
  short* dtile = ybuf + (long)tile * DIMC * 64;
  #pragma unroll
  for (int k = 0; k < 8; ++k) {
    int q4 = tid + 256 * k;
    int c = q4 & 255, pd = (q4 >> 8) * 8;
    bf16x8 v = *(const bf16x8*)(s_del + c * 72 + pd);
    *(bf16x8*)(dtile + c * 64 + pd) = v;
  }
}

// ---------------------------------------------------------------------------
// epi_k: dense, fully coalesced. out = x + (active ? delta : 0).
// ---------------------------------------------------------------------------
__global__ __launch_bounds__(256) void epi_k(
    const float* __restrict__ x, const int* __restrict__ mask,
    const short* __restrict__ delta, float* __restrict__ out) {
  const int NU = 32 * DIMC * HW * 7;            // units of 8 floats
  int stride = gridDim.x * 256;
  for (int u = blockIdx.x * 256 + threadIdx.x; u < NU; u += stride) {
    int wb = u % 7; int t1 = u / 7;
    int h = t1 % 56; int t2 = t1 / 56;
    int c = t2 & 255; int b = t2 >> 8;
    int g = ((b * DIMC + c) * HW + h) * HW + wb * 8;
    f32x4 x0 = *(const f32x4*)(x + g);
    f32x4 x1 = *(const f32x4*)(x + g + 4);
    int tile = (b * 7 + (h >> 3)) * 7 + wb;
    if (mask[tile]) {
      bf16x8 d = *(const bf16x8*)(delta + ((long)tile * DIMC + c) * 64 + (h & 7) * 8);
      #pragma unroll
      for (int i = 0; i < 4; ++i) { x0[i] += bf2f(d[i]); x1[i] += bf2f(d[4 + i]); }
    }
    *(f32x4*)(out + g) = x0;
    *(f32x4*)(out + g + 4) = x1;
  }
}

extern "C" void kernel_launch(void* const* d_in, const int* in_sizes, int n_in,
                              void* d_out, int out_size, void* d_ws, size_t ws_size,
                              hipStream_t stream) {
  const float* x    = (const float*)d_in[0];
  const int*   mask = (const int*)d_in[1];
  const float* dw_w = (const float*)d_in[2];
  const float* dw_b = (const float*)d_in[3];
  const float* ln_w = (const float*)d_in[4];
  const float* ln_b = (const float*)d_in[5];
  const float* w1   = (const float*)d_in[6];
  const float* b1   = (const float*)d_in[7];
  const float* w2   = (const float*)d_in[8];
  const float* b2   = (const float*)d_in[9];
  const float* gm   = (const float*)d_in[10];
  float* out = (float*)d_out;

  short* w1p  = (short*)d_ws;                   // 512 KB
  short* w2p  = w1p + 512 * 512;                // 512 KB
  short* ybuf = w2p + 512 * 512;                // 51.4 MB

  prep_pack<<<256, 256, 0, stream>>>(w1, w2, w1p, w2p);
  conv_k<<<12544, 256, 0, stream>>>(x, mask, dw_w, dw_b, ybuf);
  mlp_k<<<1568, 256, 0, stream>>>(mask, ln_w, ln_b, b1, b2, gm, w1p, w2p, ybuf);
  epi_k<<<4096, 256, 0, stream>>>(x, mask, ybuf, out);
}

// Round 2
// 372.706 us; speedup vs baseline: 1.0810x; 1.0810x over previous
//
#include <hip/hip_runtime.h>
#include <math.h>

#define HW   56
#define DIMC 256
#define HID  1024

typedef __attribute__((ext_vector_type(8))) short bf16x8;
typedef __attribute__((ext_vector_type(4))) float f32x4;

__device__ __forceinline__ short f2bf(float f) {
  union { float fv; unsigned u; } v; v.fv = f;
  unsigned r = v.u + 0x7fffu + ((v.u >> 16) & 1u);
  return (short)(r >> 16);
}
__device__ __forceinline__ float bf2f(short s) {
  union { unsigned u; float fv; } v; v.u = ((unsigned)(unsigned short)s) << 16;
  return v.fv;
}
// gelu via sigmoid: v*sigmoid(1.702v). rcp (1-ulp approx) is fine: error is
// scaled by gamma=1e-6 before it reaches the output.
__device__ __forceinline__ float gelu_fast(float v) {
  float e = exp2f(-2.4556260f * v);
  return v * __builtin_amdgcn_rcpf(1.f + e);
}
// pack 8 f32 -> 8 OCP e4m3 bytes in one i64 (byte j = value j; A and B use the
// same j-indexing so any HW k-permutation within the 8-group cancels in MFMA).
__device__ __forceinline__ long pk8(float f0, float f1, float f2, float f3,
                                    float f4, float f5, float f6, float f7) {
  int lo = __builtin_amdgcn_cvt_pk_fp8_f32(f0, f1, 0, false);
  lo = __builtin_amdgcn_cvt_pk_fp8_f32(f2, f3, lo, true);
  int hi = __builtin_amdgcn_cvt_pk_fp8_f32(f4, f5, 0, false);
  hi = __builtin_amdgcn_cvt_pk_fp8_f32(f6, f7, hi, true);
  return ((long)(unsigned)lo) | ((long)hi << 32);
}
__device__ __forceinline__ char f2fp8(float f) {
  return (char)(__builtin_amdgcn_cvt_pk_fp8_f32(f, f, 0, false) & 0xff);
}

// ---------------------------------------------------------------------------
// prep_pack: weights -> fp8 MFMA-fragment-major (frag = 64 lanes x 8B = 512B).
//  w1p frag (ch*2+nh)*8+k8 : n=ch*32+nh*16+l15, k=k8*32+q*8+j, elem w1[k][n]
//  w2p frag ch*16+nt2      : k=ch*32+q*8+j, c=nt2*16+l15,      elem w2[k][c]
// ---------------------------------------------------------------------------
__global__ void prep_pack(const float* __restrict__ w1, const float* __restrict__ w2,
                          long* __restrict__ w1p, long* __restrict__ w2p) {
  int g = blockIdx.x * 256 + threadIdx.x;
  int f = g >> 6, lane = g & 63;
  int l15 = lane & 15, q = lane >> 4;
  float t[8];
  if (f < 512) {
    int k8 = f & 7, tt = f >> 3, nt = tt & 1, ch = tt >> 1;
    int n = ch * 32 + nt * 16 + l15;
    int k = k8 * 32 + q * 8;
    #pragma unroll
    for (int j = 0; j < 8; ++j) t[j] = w1[(k + j) * HID + n];
    w1p[f * 64 + lane] = pk8(t[0], t[1], t[2], t[3], t[4], t[5], t[6], t[7]);
  } else {
    int f2 = f - 512;
    int nt2 = f2 & 15, ch = f2 >> 4;
    int k = ch * 32 + q * 8;
    int c = nt2 * 16 + l15;
    #pragma unroll
    for (int j = 0; j < 8; ++j) t[j] = w2[(k + j) * DIMC + c];
    w2p[f2 * 64 + lane] = pk8(t[0], t[1], t[2], t[3], t[4], t[5], t[6], t[7]);
  }
}

// ---------------------------------------------------------------------------
// conv_k: depthwise 7x7 + bias, active tiles only. Patch staged as aligned
// 16-float windows [w0-4, w0+12): 4 f32x4 per (c,r) row, compile-time w-edge
// masking. LDS [c][r][20] -> 2-way banks on sliding reads (free).
// ---------------------------------------------------------------------------
__global__ __launch_bounds__(256, 3) void conv_k(
    const float* __restrict__ x, const int* __restrict__ mask,
    const float* __restrict__ dw_w, const float* __restrict__ dw_b,
    short* __restrict__ ybuf) {
  __shared__ __align__(16) float s_patch[32 * 14 * 20];   // 35840 B
  __shared__ float s_wt[32 * 49];
  __shared__ __align__(16) short s_yout[32 * 64];

  int bid = blockIdx.x;
  int cgi = bid & 7; int t1 = bid >> 3;
  int wb = t1 % 7; int t2 = t1 / 7; int hb = t2 % 7; int b = t2 / 7;
  int tile = (b * 7 + hb) * 7 + wb;
  if (!mask[tile]) return;

  int tid = threadIdx.x;
  int h0 = hb * 8, w0 = wb * 8, cg0 = cgi * 32;

  for (int i = tid; i < 32 * 49; i += 256) s_wt[i] = dw_w[cg0 * 49 + i];

  // 32c x 14r x 4 vec-slots = 1792 slots, 7 per thread
  #pragma unroll
  for (int it = 0; it < 7; ++it) {
    int slot = tid + 256 * it;
    int j = slot & 3, row = slot >> 2;        // row = c*14 + r
    int c = row / 14, r = row - c * 14;
    int gh = h0 - 3 + r;
    f32x4 v = (f32x4){0.f, 0.f, 0.f, 0.f};
    bool ok = (gh >= 0) && (gh < HW) && !(wb == 0 && j == 0) && !(wb == 6 && j == 3);
    if (ok)
      v = *(const f32x4*)(x + ((long)(b * DIMC + cg0 + c) * HW + gh) * HW + (w0 - 4) + 4 * j);
    *(f32x4*)(s_patch + c * 280 + r * 20 + 4 * j) = v;
  }
  __syncthreads();

  int cl = tid >> 3, wq = tid & 7;
  float wt[49];
  #pragma unroll
  for (int j = 0; j < 49; ++j) wt[j] = s_wt[cl * 49 + j];
  float y[8] = {0.f, 0.f, 0.f, 0.f, 0.f, 0.f, 0.f, 0.f};
  #pragma unroll
  for (int r = 0; r < 14; ++r) {
    float row[7];
    #pragma unroll
    for (int j = 0; j < 7; ++j) row[j] = s_patch[cl * 280 + r * 20 + wq + 1 + j];
    #pragma unroll
    for (int dy = 0; dy < 7; ++dy) {
      int hh = r - dy;
      if (hh >= 0 && hh < 8) {
        #pragma unroll
        for (int dx = 0; dx < 7; ++dx) y[hh] += row[dx] * wt[dy * 7 + dx];
      }
    }
  }
  float db = dw_b[cg0 + cl];
  #pragma unroll
  for (int hh = 0; hh < 8; ++hh)
    s_yout[cl * 64 + hh * 8 + wq] = f2bf(y[hh] + db);
  __syncthreads();

  int c = tid >> 3, pd = (tid & 7) * 8;
  bf16x8 v = *(const bf16x8*)(s_yout + c * 64 + pd);
  *(bf16x8*)(ybuf + ((long)tile * DIMC + cg0 + c) * 64 + pd) = v;
}

// ---------------------------------------------------------------------------
// mlp_k v4 (fp8): A-frags, W1, W2 and h all OCP e4m3; MFMA 16x16x32_fp8_fp8
// (same rate as bf16, half the operand bytes). Per-chunk weight stream drops
// 12KB -> 6KB/wave (the R1 stall source), operand VGPRs halve, h-LDS halves.
// LN kept in bf16/f32; all fp8 error is scaled by gamma=1e-6 at the output.
// LDS: s_a/s_del 36864 | h(fp8 dbuf) 5120 | stats 4608 = 46592 -> 3 blocks/CU.
// launch_bounds(256,3): cap regs so 3 blocks actually fit.
// ---------------------------------------------------------------------------
__global__ __launch_bounds__(256, 3) void mlp_k(
    const int* __restrict__ mask,
    const float* __restrict__ ln_w, const float* __restrict__ ln_b,
    const float* __restrict__ b1v, const float* __restrict__ b2v,
    const float* __restrict__ gammav,
    const long* __restrict__ w1p, const long* __restrict__ w2p,
    short* __restrict__ ybuf) {
  __shared__ __align__(16) char smem[46592];
  short* s_a   = (short*)smem;                  // [p 64][264] bf16 (LN'd A)
  short* s_del = (short*)smem;                  // alias: [c 256][72] bf16
  char*  s_h8  = smem + 36864;                  // 2 x [64 m][40] fp8
  float* s_p1  = (float*)(smem + 41984);
  float* s_p2  = (float*)(smem + 43008);
  float* s_mu  = (float*)(smem + 44032);
  float* s_rs  = (float*)(smem + 44288);
  float* s_lnw = (float*)(smem + 44544);
  float* s_lnb = (float*)(smem + 45568);

  int tile = blockIdx.x;
  if (!mask[tile]) return;
  int tid = threadIdx.x;
  const short* ytile = ybuf + (long)tile * DIMC * 64;

  s_lnw[tid] = ln_w[tid];
  s_lnb[tid] = ln_b[tid];
  // load ybuf [c][p] -> transpose into s_a [p][c]; lane-per-channel so the
  // scalar u16 LDS writes spread across banks (c consecutive per lane).
  #pragma unroll
  for (int k = 0; k < 8; ++k) {
    int q4 = tid + 256 * k;
    int c = q4 & 255, pd = (q4 >> 8) * 8;
    bf16x8 v = *(const bf16x8*)(ytile + c * 64 + pd);
    #pragma unroll
    for (int j = 0; j < 8; ++j) s_a[(pd + j) * 264 + c] = v[j];
  }
  __syncthreads();

  // LN stats via vector reads, values kept in registers for the normalize
  {
    int p = tid & 63, cq = tid >> 6;
    bf16x8 va[8];
    float s1 = 0.f, s2 = 0.f;
    #pragma unroll
    for (int i = 0; i < 8; ++i) {
      va[i] = *(const bf16x8*)(s_a + p * 264 + cq * 64 + i * 8);
      #pragma unroll
      for (int j = 0; j < 8; ++j) {
        float f = bf2f(va[i][j]);
        s1 += f; s2 += f * f;
      }
    }
    s_p1[cq * 64 + p] = s1; s_p2[cq * 64 + p] = s2;
    __syncthreads();
    if (tid < 64) {
      float t1 = s_p1[tid] + s_p1[64 + tid] + s_p1[128 + tid] + s_p1[192 + tid];
      float t2 = s_p2[tid] + s_p2[64 + tid] + s_p2[128 + tid] + s_p2[192 + tid];
      float mu = t1 * (1.f / 256.f);
      float var = t2 * (1.f / 256.f) - mu * mu;
      s_mu[tid] = mu; s_rs[tid] = rsqrtf(var + 1e-6f);
    }
    __syncthreads();
    float mu = s_mu[p], rs = s_rs[p];
    #pragma unroll
    for (int i = 0; i < 8; ++i) {
      int c0 = cq * 64 + i * 8;
      bf16x8 v = va[i];
      #pragma unroll
      for (int j = 0; j < 8; ++j)
        v[j] = f2bf((bf2f(v[j]) - mu) * rs * s_lnw[c0 + j] + s_lnb[c0 + j]);
      *(bf16x8*)(s_a + p * 264 + c0) = v;
    }
  }
  __syncthreads();

  const int wv = tid >> 6, lane = tid & 63;
  const int l15 = lane & 15, q = lane >> 4;
  const int mh = wv & 1, nh = wv >> 1;          // GEMM1: 2M x 2N wave split

  // hoist the loop-invariant GEMM1 A-operand into fp8 registers (32 VGPRs)
  const short* aRow0 = s_a + (32 * mh + l15) * 264 + q * 8;
  const short* aRow1 = s_a + (32 * mh + 16 + l15) * 264 + q * 8;
  long a0f[8], a1f[8];
  #pragma unroll
  for (int k8 = 0; k8 < 8; ++k8) {
    bf16x8 v0 = *(const bf16x8*)(aRow0 + k8 * 32);
    bf16x8 v1 = *(const bf16x8*)(aRow1 + k8 * 32);
    a0f[k8] = pk8(bf2f(v0[0]), bf2f(v0[1]), bf2f(v0[2]), bf2f(v0[3]),
                  bf2f(v0[4]), bf2f(v0[5]), bf2f(v0[6]), bf2f(v0[7]));
    a1f[k8] = pk8(bf2f(v1[0]), bf2f(v1[1]), bf2f(v1[2]), bf2f(v1[3]),
                  bf2f(v1[4]), bf2f(v1[5]), bf2f(v1[6]), bf2f(v1[7]));
  }

  f32x4 z[4][4];                                // [jt][Mt], c = wv*64+jt*16+l15
  #pragma unroll
  for (int jt = 0; jt < 4; ++jt)
    #pragma unroll
    for (int Mt = 0; Mt < 4; ++Mt) z[jt][Mt] = (f32x4){0.f, 0.f, 0.f, 0.f};

  long w1r[8];                                  // prefetched W1 frags (ch=0)
  #pragma unroll
  for (int k8 = 0; k8 < 8; ++k8)
    w1r[k8] = w1p[(long)(nh * 8 + k8) * 64 + lane];

  for (int ch = 0; ch < 32; ++ch) {
    // issue W2 frags + bias now; consumed after barrier / after GEMM1
    long w2r[4];
    #pragma unroll
    for (int jt = 0; jt < 4; ++jt)
      w2r[jt] = w2p[(long)(ch * 16 + wv * 4 + jt) * 64 + lane];
    float bb = b1v[ch * 32 + 16 * nh + l15];

    f32x4 acc0 = (f32x4){0.f, 0.f, 0.f, 0.f};
    f32x4 acc1 = (f32x4){0.f, 0.f, 0.f, 0.f};
    __builtin_amdgcn_s_setprio(1);
    #pragma unroll
    for (int k8 = 0; k8 < 8; ++k8) {
      acc0 = __builtin_amdgcn_mfma_f32_16x16x32_fp8_fp8(a0f[k8], w1r[k8], acc0, 0, 0, 0);
      acc1 = __builtin_amdgcn_mfma_f32_16x16x32_fp8_fp8(a1f[k8], w1r[k8], acc1, 0, 0, 0);
    }
    __builtin_amdgcn_s_setprio(0);
    long w1n[8];                                // prefetch next chunk's W1
    if (ch < 31) {
      #pragma unroll
      for (int k8 = 0; k8 < 8; ++k8)
        w1n[k8] = w1p[(long)(((ch + 1) * 2 + nh) * 8 + k8) * 64 + lane];
    }
    char* hb = s_h8 + (ch & 1) * 2560;
    #pragma unroll
    for (int r = 0; r < 4; ++r) {
      hb[(32 * mh + 4 * q + r) * 40 + 16 * nh + l15]      = f2fp8(gelu_fast(acc0[r] + bb));
      hb[(32 * mh + 16 + 4 * q + r) * 40 + 16 * nh + l15] = f2fp8(gelu_fast(acc1[r] + bb));
    }
    __syncthreads();                            // h[ch&1] complete
    __builtin_amdgcn_s_setprio(1);
    #pragma unroll
    for (int Mt = 0; Mt < 4; ++Mt) {
      long aH = *(const long*)(hb + (16 * Mt + l15) * 40 + q * 8);
      #pragma unroll
      for (int jt = 0; jt < 4; ++jt)
        z[jt][Mt] = __builtin_amdgcn_mfma_f32_16x16x32_fp8_fp8(aH, w2r[jt], z[jt][Mt], 0, 0, 0);
    }
    __builtin_amdgcn_s_setprio(0);
    if (ch < 31) {
      #pragma unroll
      for (int k8 = 0; k8 < 8; ++k8) w1r[k8] = w1n[k8];
    }
  }

  // epilogue: delta = (z+b2)*gamma -> s_del [c][72] -> ybuf in place
  #pragma unroll
  for (int jt = 0; jt < 4; ++jt) {
    int c = wv * 64 + jt * 16 + l15;
    float bb = b2v[c], gm = gammav[c];
    #pragma unroll
    for (int Mt = 0; Mt < 4; ++Mt) {
      #pragma unroll
      for (int r = 0; r < 4; ++r)
        s_del[c * 72 + 16 * Mt + 4 * q + r] = f2bf((z[jt][Mt][r] + bb) * gm);
    }
  }
  __syncthreads();
  short* dtile = ybuf + (long)tile * DIMC * 64;
  #pragma unroll
  for (int k = 0; k < 8; ++k) {
    int q4 = tid + 256 * k;
    int c = q4 & 255, pd = (q4 >> 8) * 8;
    bf16x8 v = *(const bf16x8*)(s_del + c * 72 + pd);
    *(bf16x8*)(dtile + c * 64 + pd) = v;
  }
}

// ---------------------------------------------------------------------------
// epi_k: dense, fully coalesced. out = x + (active ? delta : 0).
// ---------------------------------------------------------------------------
__global__ __launch_bounds__(256) void epi_k(
    const float* __restrict__ x, const int* __restrict__ mask,
    const short* __restrict__ delta, float* __restrict__ out) {
  const int NU = 32 * DIMC * HW * 7;            // units of 8 floats
  int stride = gridDim.x * 256;
  for (int u = blockIdx.x * 256 + threadIdx.x; u < NU; u += stride) {
    int wb = u % 7; int t1 = u / 7;
    int h = t1 % 56; int t2 = t1 / 56;
    int c = t2 & 255; int b = t2 >> 8;
    int g = ((b * DIMC + c) * HW + h) * HW + wb * 8;
    f32x4 x0 = *(const f32x4*)(x + g);
    f32x4 x1 = *(const f32x4*)(x + g + 4);
    int tile = (b * 7 + (h >> 3)) * 7 + wb;
    if (mask[tile]) {
      bf16x8 d = *(const bf16x8*)(delta + ((long)tile * DIMC + c) * 64 + (h & 7) * 8);
      #pragma unroll
      for (int i = 0; i < 4; ++i) { x0[i] += bf2f(d[i]); x1[i] += bf2f(d[4 + i]); }
    }
    *(f32x4*)(out + g) = x0;
    *(f32x4*)(out + g + 4) = x1;
  }
}

extern "C" void kernel_launch(void* const* d_in, const int* in_sizes, int n_in,
                              void* d_out, int out_size, void* d_ws, size_t ws_size,
                              hipStream_t stream) {
  const float* x    = (const float*)d_in[0];
  const int*   mask = (const int*)d_in[1];
  const float* dw_w = (const float*)d_in[2];
  const float* dw_b = (const float*)d_in[3];
  const float* ln_w = (const float*)d_in[4];
  const float* ln_b = (const float*)d_in[5];
  const float* w1   = (const float*)d_in[6];
  const float* b1   = (const float*)d_in[7];
  const float* w2   = (const float*)d_in[8];
  const float* b2   = (const float*)d_in[9];
  const float* gm   = (const float*)d_in[10];
  float* out = (float*)d_out;

  long* w1p  = (long*)d_ws;                     // 256 KB (512 frags x 512B)
  long* w2p  = w1p + 512 * 64;                  // 256 KB
  short* ybuf = (short*)(w2p + 512 * 64);       // 51.4 MB

  prep_pack<<<256, 256, 0, stream>>>(w1, w2, w1p, w2p);
  conv_k<<<12544, 256, 0, stream>>>(x, mask, dw_w, dw_b, ybuf);
  mlp_k<<<1568, 256, 0, stream>>>(mask, ln_w, ln_b, b1, b2, gm, w1p, w2p, ybuf);
  epi_k<<<4096, 256, 0, stream>>>(x, mask, ybuf, out);
}